// Round 10
// baseline (893.812 us; speedup 1.0000x reference)
//
#include <hip/hip_runtime.h>
#include <stdint.h>

#define HID 2048
#define HKK 8                          // HID / (64 lanes * 4 floats)
#define HSQ ((size_t)HID * HID)        // one gate-block of a weight matrix
#define LSTR ((size_t)4 * HID * HID)   // per-layer stride of W_ih/W_hh
#define GROWS (4 * HID)                // 8192 gate-rows per matrix
#define NOPS 8
#define MSZ ((size_t)GROWS * HID)      // 16777216 elements per weight matrix

// ws layout (float offsets)
#define OFF_H0   0                     // [2][HID] ping-pong
#define OFF_H1   4096                  // [HID]
#define OFF_C0   6144                  // [HID]
#define OFF_C1   8192                  // [HID]
#define OFF_P1   10240                 // [GROWS] layer-1 partial gates
#define OFF_SC   18432                 // lp, ent, sel(int), pad
#define OFF_PIH  18436                 // [9][GROWS] W_ih0@emb + b0
#define WS_FLOATS (OFF_PIH + 9 * GROWS)        // 92164
#define OFF_BW   WS_FLOATS                     // bf16 weights (ushort view)
#define WS_FLOATS_BF (OFF_BW + (3 * MSZ) / 2)

typedef unsigned int uv4_ __attribute__((ext_vector_type(4)));

__device__ __forceinline__ uint32_t rotl32_(uint32_t v, int d) {
  return (v << d) | (v >> (32 - d));
}

// JAX threefry2x32, 20 rounds, key (k0,k1), counter (x0,x1)
__device__ __forceinline__ void tf2x32(uint32_t k0, uint32_t k1,
                                       uint32_t x0, uint32_t x1,
                                       uint32_t& o0, uint32_t& o1) {
  uint32_t k2 = k0 ^ k1 ^ 0x1BD11BDAu;
  x0 += k0; x1 += k1;
#define TFR(r) { x0 += x1; x1 = rotl32_(x1, r); x1 ^= x0; }
  TFR(13) TFR(15) TFR(26) TFR(6)
  x0 += k1; x1 += k2 + 1u;
  TFR(17) TFR(29) TFR(16) TFR(24)
  x0 += k2; x1 += k0 + 2u;
  TFR(13) TFR(15) TFR(26) TFR(6)
  x0 += k0; x1 += k1 + 3u;
  TFR(17) TFR(29) TFR(16) TFR(24)
  x0 += k1; x1 += k2 + 4u;
  TFR(13) TFR(15) TFR(26) TFR(6)
  x0 += k2; x1 += k0 + 5u;
#undef TFR
  o0 = x0; o1 = x1;
}

__device__ __forceinline__ float sigm_(float x) { return 1.0f / (1.0f + expf(-x)); }

__device__ __forceinline__ float wave_red(float s) {
#pragma unroll
  for (int o = 32; o > 0; o >>= 1) s += __shfl_xor(s, o, 64);
  return s;
}

__device__ __forceinline__ float blo_(uint32_t u) {
  return __uint_as_float(u << 16);
}
__device__ __forceinline__ float bhi_(uint32_t u) {
  return __uint_as_float(u & 0xffff0000u);
}
__device__ __forceinline__ uint32_t f2b_(float f) {  // fp32 -> bf16 bits, RNE
  uint32_t u = __float_as_uint(f);
  return (u + 0x7fffu + ((u >> 16) & 1u)) >> 16;
}

// non-temporal float4 load (one-shot fp32 weight streams; keep caches for bw)
__device__ __forceinline__ float4 ldnt_f4(const float* p) {
  uv4_ u = __builtin_nontemporal_load((const uv4_*)p);
  float4 r;
  r.x = __uint_as_float(u.x); r.y = __uint_as_float(u.y);
  r.z = __uint_as_float(u.z); r.w = __uint_as_float(u.w);
  return r;
}

// ---------------- fp32 dot helper (fallback path) ----------------
__device__ __forceinline__ void dot4(const float* __restrict__ wrow,
                                     const float* __restrict__ vec,
                                     int lane, float* __restrict__ g4) {
  float4 acc[4];
#pragma unroll
  for (int g = 0; g < 4; ++g) acc[g] = make_float4(0.f, 0.f, 0.f, 0.f);
#pragma unroll
  for (int kk = 0; kk < HKK; ++kk) {
    const int off = kk * 256 + lane * 4;
    const float4 v = *(const float4*)(vec + off);
#pragma unroll
    for (int g = 0; g < 4; ++g) {
      const float4 w = *(const float4*)(wrow + (size_t)g * HSQ + off);
      acc[g].x = fmaf(w.x, v.x, acc[g].x);
      acc[g].y = fmaf(w.y, v.y, acc[g].y);
      acc[g].z = fmaf(w.z, v.z, acc[g].z);
      acc[g].w = fmaf(w.w, v.w, acc[g].w);
    }
  }
#pragma unroll
  for (int g = 0; g < 4; ++g) {
    float s = (acc[g].x + acc[g].y) + (acc[g].z + acc[g].w);
    g4[g] = wave_red(s);
  }
}

// ---------------- bf16 dot helper: MLP-hoisted ----------------
// All 16 weight uint4 + 8 vec float4 loads issued BEFORE any FMA (max
// outstanding loads per wave). Per-accumulator FMA order identical to the
// R5/R6/R8 dot4b (for each g: kk=0..3, same 8-FMA sequence) -> bit-identical.
__device__ __forceinline__ void dot4b(const ushort* __restrict__ wrow,
                                      const float* __restrict__ vec,
                                      int lane, float* __restrict__ g4) {
  uint4 w[4][4];
  float4 v0[4], v1[4];
#pragma unroll
  for (int kk = 0; kk < 4; ++kk) {
    const int off = kk * 512 + lane * 8;
#pragma unroll
    for (int g = 0; g < 4; ++g)
      w[kk][g] = *(const uint4*)(wrow + (size_t)g * HSQ + off);
    v0[kk] = *(const float4*)(vec + off);
    v1[kk] = *(const float4*)(vec + off + 4);
  }
  float4 acc[4];
#pragma unroll
  for (int g = 0; g < 4; ++g) acc[g] = make_float4(0.f, 0.f, 0.f, 0.f);
#pragma unroll
  for (int kk = 0; kk < 4; ++kk) {
#pragma unroll
    for (int g = 0; g < 4; ++g) {
      acc[g].x = fmaf(blo_(w[kk][g].x), v0[kk].x, acc[g].x);
      acc[g].y = fmaf(bhi_(w[kk][g].x), v0[kk].y, acc[g].y);
      acc[g].z = fmaf(blo_(w[kk][g].y), v0[kk].z, acc[g].z);
      acc[g].w = fmaf(bhi_(w[kk][g].y), v0[kk].w, acc[g].w);
      acc[g].x = fmaf(blo_(w[kk][g].z), v1[kk].x, acc[g].x);
      acc[g].y = fmaf(bhi_(w[kk][g].z), v1[kk].y, acc[g].y);
      acc[g].z = fmaf(blo_(w[kk][g].w), v1[kk].z, acc[g].z);
      acc[g].w = fmaf(bhi_(w[kk][g].w), v1[kk].w, acc[g].w);
    }
  }
#pragma unroll
  for (int g = 0; g < 4; ++g) {
    float s = (acc[g].x + acc[g].y) + (acc[g].z + acc[g].w);
    g4[g] = wave_red(s);
  }
}

// ---------------- sampler (shared) ----------------
__device__ __forceinline__ int sample_step(
    const float* __restrict__ w_soft_w, const float* __restrict__ w_soft_b,
    float* __restrict__ out, float* __restrict__ ws, int t, int sidx, int K,
    bool writer) {
  __shared__ float s_raw[NOPS];
  __shared__ int s_sel;
  const int tid = threadIdx.x, lane = tid & 63, wv = tid >> 6;
  const float* h1 = ws + OFF_H1;
  const int r0 = wv * 2, r1 = r0 + 1;
  float4 a0 = make_float4(0.f, 0.f, 0.f, 0.f);
  float4 a1 = make_float4(0.f, 0.f, 0.f, 0.f);
  for (int kk = 0; kk < HKK; ++kk) {
    const int off = kk * 256 + lane * 4;
    const float4 hv = *(const float4*)(h1 + off);
    const float4 wa = *(const float4*)(w_soft_w + (size_t)r0 * HID + off);
    const float4 wb = *(const float4*)(w_soft_w + (size_t)r1 * HID + off);
    a0.x = fmaf(wa.x, hv.x, a0.x); a0.y = fmaf(wa.y, hv.y, a0.y);
    a0.z = fmaf(wa.z, hv.z, a0.z); a0.w = fmaf(wa.w, hv.w, a0.w);
    a1.x = fmaf(wb.x, hv.x, a1.x); a1.y = fmaf(wb.y, hv.y, a1.y);
    a1.z = fmaf(wb.z, hv.z, a1.z); a1.w = fmaf(wb.w, hv.w, a1.w);
  }
  float s0 = wave_red((a0.x + a0.y) + (a0.z + a0.w));
  float s1 = wave_red((a1.x + a1.y) + (a1.z + a1.w));
  if (lane == 0) {
    s_raw[r0] = s0 + w_soft_b[r0];
    s_raw[r1] = s1 + w_soft_b[r1];
  }
  __syncthreads();
  if (tid == 0) {
    float logits[NOPS];
#pragma unroll
    for (int r = 0; r < NOPS; ++r) logits[r] = tanhf(s_raw[r] * 0.2f);
    uint32_t k0, k1;
    tf2x32(0u, 1u, 0u, (uint32_t)t, k0, k1);  // partitionable split
    const float TINY = 1.17549435e-38f;
    int op = 0;
    float best = -1e30f;
#pragma unroll
    for (int r = 0; r < NOPS; ++r) {
      uint32_t o0, o1;
      tf2x32(k0, k1, 0u, (uint32_t)r, o0, o1);  // random_bits: o0^o1
      const uint32_t bits = o0 ^ o1;
      const float f = __uint_as_float((bits >> 9) | 0x3f800000u) - 1.0f;
      const float u = fmaxf(f + TINY, TINY);
      const float g = -logf(-logf(u));
      const float y = g + logits[r];
      if (y > best) { best = y; op = r; }  // first-max (jnp.argmax)
    }
    if (writer) {
      float mx = logits[0];
#pragma unroll
      for (int r = 1; r < NOPS; ++r) mx = fmaxf(mx, logits[r]);
      float se = 0.f;
#pragma unroll
      for (int r = 0; r < NOPS; ++r) se += expf(logits[r] - mx);
      const float lse = mx + logf(se);
      const float lp = ws[OFF_SC] + (logits[op] - lse);
      float es = 0.f;
#pragma unroll
      for (int r = 0; r < NOPS; ++r) {
        const float lr = logits[r] - lse;
        es += expf(lr) * lr;
      }
      const float ent = ws[OFF_SC + 1] - es;
      ws[OFF_SC] = lp;
      ws[OFF_SC + 1] = ent;
      out[sidx] = (float)op;
#pragma unroll
      for (int r = 0; r < NOPS; ++r) out[K + sidx * NOPS + r] = logits[r];
      out[9 * K] = lp;
      out[9 * K + 1] = ent;
    }
    s_sel = op;
  }
  __syncthreads();
  return s_sel;
}

// zero states + scalars
__global__ __launch_bounds__(256) void k_init(float* __restrict__ ws) {
  const int gid = blockIdx.x * 256 + threadIdx.x;
  for (int i = gid; i < OFF_P1; i += gridDim.x * 256) ws[i] = 0.f;
  if (gid < 4) ws[OFF_SC + gid] = 0.f;
}

// pih[k][r] = W_ih0[r,:]@w_emb[k,:] + b_ih0[r] + b_hh0[r]  (NT weight reads)
__global__ __launch_bounds__(256) void k_pre(const float* __restrict__ w_emb,
                                             const float* __restrict__ W_ih,
                                             const float* __restrict__ b_ih,
                                             const float* __restrict__ b_hh,
                                             float* __restrict__ ws) {
  const int tid = threadIdx.x, lane = tid & 63, wv = tid >> 6;
  const int r = blockIdx.x * 4 + wv;  // 0..8191
  const float* wr = W_ih + (size_t)r * HID;
  float4 acc[NOPS + 1];
#pragma unroll
  for (int k = 0; k <= NOPS; ++k) acc[k] = make_float4(0.f, 0.f, 0.f, 0.f);
  for (int kk = 0; kk < HKK; ++kk) {
    const int off = kk * 256 + lane * 4;
    const float4 w = ldnt_f4(wr + off);
#pragma unroll
    for (int k = 0; k <= NOPS; ++k) {
      const float4 e = *(const float4*)(w_emb + (size_t)k * HID + off);
      acc[k].x = fmaf(w.x, e.x, acc[k].x);
      acc[k].y = fmaf(w.y, e.y, acc[k].y);
      acc[k].z = fmaf(w.z, e.z, acc[k].z);
      acc[k].w = fmaf(w.w, e.w, acc[k].w);
    }
  }
  const float bias = b_ih[r] + b_hh[r];
#pragma unroll
  for (int k = 0; k <= NOPS; ++k) {
    float s = (acc[k].x + acc[k].y) + (acc[k].z + acc[k].w);
    s = wave_red(s);
    if (lane == 0) ws[OFF_PIH + (size_t)k * GROWS + r] = s + bias;
  }
}

// convert W_hh0, W_hh1, W_ih1 -> bf16 (grid-stride; NT source reads)
__global__ __launch_bounds__(256) void k_cvt(const float* __restrict__ W_ih,
                                             const float* __restrict__ W_hh,
                                             ushort* __restrict__ bw) {
  const size_t NT = (3 * MSZ) / 8;
  const size_t stride = (size_t)gridDim.x * 256;
  for (size_t task = (size_t)blockIdx.x * 256 + threadIdx.x; task < NT;
       task += stride) {
    const int m = (int)(task >> 21);
    const size_t base = (task & 2097151u) * 8;
    const float* src = (m == 0) ? W_hh : (m == 1 ? W_hh + LSTR : W_ih + LSTR);
    ushort* dst = bw + (size_t)m * MSZ;
    const float4 a = ldnt_f4(src + base);
    const float4 b = ldnt_f4(src + base + 4);
    uint4 o;
    o.x = f2b_(a.x) | (f2b_(a.y) << 16);
    o.y = f2b_(a.z) | (f2b_(a.w) << 16);
    o.z = f2b_(b.x) | (f2b_(b.y) << 16);
    o.w = f2b_(b.z) | (f2b_(b.w) << 16);
    *(uint4*)(dst + base) = o;
  }
}

// step 0 specialization: h0=h1=0 -> gates0 = pih[start], p1 = biases.
__global__ __launch_bounds__(256) void k_s0(const float* __restrict__ b_ih,
                                            const float* __restrict__ b_hh,
                                            float* __restrict__ ws) {
  const int gid = blockIdx.x * 256 + threadIdx.x;
  if (gid < GROWS) {
    ws[OFF_P1 + gid] = 0.f + b_ih[GROWS + gid] + b_hh[GROWS + gid];
  } else if (gid < GROWS + HID) {
    const int j = gid - GROWS;
    const float* pih = ws + OFF_PIH + (size_t)NOPS * GROWS;
    const float gi = pih[j], gf = pih[HID + j];
    const float gg = pih[2 * HID + j], go = pih[3 * HID + j];
    const float ig = sigm_(gi);
    const float fg = sigm_(gf);
    const float g2 = tanhf(gg);
    const float og = sigm_(go);
    const float c = fg * 0.f + ig * g2;
    ws[OFF_C0 + j] = c;
    ws[OFF_H0 + HID + j] = og * tanhf(c);  // par=0 -> h0w = parity 1
  }
}

// ---- bf16 step kernels (R8-proven structure; MLP-hoisted dot4b) ----
// Phase A: 1024 blocks; blocks 0..511 = layer-0 (sampler for t_prev inline),
// blocks 512..1023 = layer-1 recurrent partial.
__global__ __launch_bounds__(256) void k_a_bf(
    const ushort* __restrict__ bw, const float* __restrict__ b_ih,
    const float* __restrict__ b_hh, const float* __restrict__ w_soft_w,
    const float* __restrict__ w_soft_b, float* __restrict__ out,
    float* __restrict__ ws, int par, int t_prev, int sidx_prev, int K,
    int flag_prev) {
  const int tid = threadIdx.x, lane = tid & 63, wv = tid >> 6;
  const int gw = blockIdx.x * 4 + wv;  // 0..4095
  const float* h0r = ws + OFF_H0 + par * HID;
  float*       h0w = ws + OFF_H0 + (par ^ 1) * HID;

  if (gw < HID) {
    int sel = NOPS;
    if (flag_prev)  // blocks 0..511 only reach here
      sel = sample_step(w_soft_w, w_soft_b, out, ws, t_prev, sidx_prev, K,
                        blockIdx.x == 0);
    const int j = gw;
    float gate[4];
    dot4b(bw + (size_t)j * HID, h0r, lane, gate);  // W_hh0 @ h0
    const float* pih = ws + OFF_PIH + (size_t)sel * GROWS;
#pragma unroll
    for (int g = 0; g < 4; ++g) gate[g] += pih[g * HID + j];
    if (lane == 0) {
      const float ig = sigm_(gate[0]);
      const float fg = sigm_(gate[1]);
      const float gg = tanhf(gate[2]);
      const float og = sigm_(gate[3]);
      const float c = fg * ws[OFF_C0 + j] + ig * gg;
      ws[OFF_C0 + j] = c;
      h0w[j] = og * tanhf(c);
    }
  } else {
    const int k = gw - HID;
    float gate[4];
    dot4b(bw + MSZ + (size_t)k * HID, ws + OFF_H1, lane, gate);  // W_hh1 @ h1
    if (lane == 0) {
#pragma unroll
      for (int g = 0; g < 4; ++g)
        ws[OFF_P1 + g * HID + k] =
            gate[g] + b_ih[GROWS + g * HID + k] + b_hh[GROWS + g * HID + k];
    }
  }
}

// Phase B: 512 blocks, layer-1 finish.
__global__ __launch_bounds__(256) void k_b_bf(const ushort* __restrict__ bw,
                                              float* __restrict__ ws, int par) {
  const int tid = threadIdx.x, lane = tid & 63, wv = tid >> 6;
  const int k = blockIdx.x * 4 + wv;  // 0..2047
  const float* h0n = ws + OFF_H0 + (par ^ 1) * HID;
  float gate[4];
  dot4b(bw + 2 * MSZ + (size_t)k * HID, h0n, lane, gate);  // W_ih1 @ h0_new
  if (lane == 0) {
#pragma unroll
    for (int g = 0; g < 4; ++g) gate[g] += ws[OFF_P1 + g * HID + k];
    const float ig = sigm_(gate[0]);
    const float fg = sigm_(gate[1]);
    const float gg = tanhf(gate[2]);
    const float og = sigm_(gate[3]);
    const float c = fg * ws[OFF_C1 + k] + ig * gg;
    ws[OFF_C1 + k] = c;
    ws[OFF_H1 + k] = og * tanhf(c);
  }
}

// ---- fp32 fallback step kernels (R3, proven) ----
template <bool PRE>
__global__ __launch_bounds__(256) void k_a(const float* __restrict__ W_ih,
                                           const float* __restrict__ W_hh,
                                           const float* __restrict__ w_emb,
                                           const float* __restrict__ b_ih,
                                           const float* __restrict__ b_hh,
                                           float* __restrict__ ws, int par,
                                           int dyn) {
  const int tid = threadIdx.x, lane = tid & 63, wv = tid >> 6;
  const int gw = blockIdx.x * 4 + wv;
  const float* h0r = ws + OFF_H0 + par * HID;
  float*       h0w = ws + OFF_H0 + (par ^ 1) * HID;

  if (gw < HID) {
    const int j = gw;
    const int sel = dyn ? *(const int*)(ws + OFF_SC + 2) : NOPS;
    float gate[4];
    dot4(W_hh + (size_t)j * HID, h0r, lane, gate);
    if constexpr (PRE) {
      const float* pih = ws + OFF_PIH + (size_t)sel * GROWS;
#pragma unroll
      for (int g = 0; g < 4; ++g) gate[g] += pih[g * HID + j];
    } else {
      float gi[4];
      dot4(W_ih + (size_t)j * HID, w_emb + (size_t)sel * HID, lane, gi);
#pragma unroll
      for (int g = 0; g < 4; ++g)
        gate[g] += gi[g] + b_ih[g * HID + j] + b_hh[g * HID + j];
    }
    if (lane == 0) {
      const float ig = sigm_(gate[0]);
      const float fg = sigm_(gate[1]);
      const float gg = tanhf(gate[2]);
      const float og = sigm_(gate[3]);
      const float c = fg * ws[OFF_C0 + j] + ig * gg;
      ws[OFF_C0 + j] = c;
      h0w[j] = og * tanhf(c);
    }
  } else {
    const int k = gw - HID;
    float gate[4];
    dot4(W_hh + LSTR + (size_t)k * HID, ws + OFF_H1, lane, gate);
    if (lane == 0) {
#pragma unroll
      for (int g = 0; g < 4; ++g)
        ws[OFF_P1 + g * HID + k] =
            gate[g] + b_ih[GROWS + g * HID + k] + b_hh[GROWS + g * HID + k];
    }
  }
}

__global__ __launch_bounds__(256) void k_b(const float* __restrict__ W_ih,
                                           float* __restrict__ ws, int par) {
  const int tid = threadIdx.x, lane = tid & 63, wv = tid >> 6;
  const int k = blockIdx.x * 4 + wv;
  const float* h0n = ws + OFF_H0 + (par ^ 1) * HID;
  float gate[4];
  dot4(W_ih + LSTR + (size_t)k * HID, h0n, lane, gate);
  if (lane == 0) {
#pragma unroll
    for (int g = 0; g < 4; ++g) gate[g] += ws[OFF_P1 + g * HID + k];
    const float ig = sigm_(gate[0]);
    const float fg = sigm_(gate[1]);
    const float gg = tanhf(gate[2]);
    const float og = sigm_(gate[3]);
    const float c = fg * ws[OFF_C1 + k] + ig * gg;
    ws[OFF_C1 + k] = c;
    ws[OFF_H1 + k] = og * tanhf(c);
  }
}

__global__ __launch_bounds__(256) void k_c(const float* __restrict__ w_soft_w,
                                           const float* __restrict__ w_soft_b,
                                           float* __restrict__ out,
                                           float* __restrict__ ws, int t,
                                           int sidx, int K) {
  const int op = sample_step(w_soft_w, w_soft_b, out, ws, t, sidx, K, true);
  if (threadIdx.x == 0) *(int*)(ws + OFF_SC + 2) = op;
}

extern "C" void kernel_launch(void* const* d_in, const int* in_sizes, int n_in,
                              void* d_out, int out_size, void* d_ws, size_t ws_size,
                              hipStream_t stream) {
  const float* w_emb    = (const float*)d_in[0];
  const float* W_ih     = (const float*)d_in[1];
  const float* W_hh     = (const float*)d_in[2];
  const float* b_ih     = (const float*)d_in[3];
  const float* b_hh     = (const float*)d_in[4];
  const float* w_soft_w = (const float*)d_in[5];
  const float* w_soft_b = (const float*)d_in[6];
  float* out            = (float*)d_out;
  float* ws             = (float*)d_ws;
  ushort* bw            = (ushort*)(ws + OFF_BW);

  // out_size = 9*K + 2 -> K -> n_nodes; schedule is host-static.
  const int K = (out_size - 2) / 9;
  int n = 0;
  while (n * (n + 1) / 2 < K) ++n;
  const int T = 2 + K + n;

  int flags[192];
  {
    int idx = 0;
    flags[idx++] = 0;
    flags[idx++] = 0;
    for (int node = 0; node < n; ++node) {
      for (int i = 0; i <= node; ++i) flags[idx++] = 1;
      flags[idx++] = 0;
    }
  }

  const bool pre = ws_size >= (size_t)WS_FLOATS * sizeof(float);
  const bool bf  = ws_size >= (size_t)WS_FLOATS_BF * sizeof(float);

  k_init<<<64, 256, 0, stream>>>(ws);
  if (pre) k_pre<<<2048, 256, 0, stream>>>(w_emb, W_ih, b_ih, b_hh, ws);

  if (bf) {
    // step 0 needs no weight matvecs (h0=h1=0): run alongside/before cvt.
    k_s0<<<(GROWS + HID + 255) / 256, 256, 0, stream>>>(b_ih, b_hh, ws);
    k_cvt<<<4096, 256, 0, stream>>>(W_ih, W_hh, bw);
    k_b_bf<<<512, 256, 0, stream>>>(bw, ws, 0);  // finish step 0
    int par = 1, cnt = 0, pf = flags[0], pidx = 0;
    if (flags[0]) { pidx = cnt; ++cnt; }
    for (int t = 1; t < T; ++t) {
      k_a_bf<<<1024, 256, 0, stream>>>(bw, b_ih, b_hh, w_soft_w, w_soft_b,
                                       out, ws, par, t - 1, pidx, K, pf);
      k_b_bf<<<512, 256, 0, stream>>>(bw, ws, par);
      if (flags[t]) { pidx = cnt; ++cnt; }
      pf = flags[t];
      par ^= 1;
    }
    return;
  }

  int par = 0, sidx = 0, prevflag = 0;
  for (int t = 0; t < T; ++t) {
    if (pre)
      k_a<true><<<1024, 256, 0, stream>>>(W_ih, W_hh, w_emb, b_ih, b_hh, ws,
                                          par, prevflag);
    else
      k_a<false><<<1024, 256, 0, stream>>>(W_ih, W_hh, w_emb, b_ih, b_hh, ws,
                                           par, prevflag);
    k_b<<<512, 256, 0, stream>>>(W_ih, ws, par);
    if (flags[t]) {
      k_c<<<1, 256, 0, stream>>>(w_soft_w, w_soft_b, out, ws, t, sidx, K);
      ++sidx;
    }
    prevflag = flags[t];
    par ^= 1;
  }
}

// Round 11
// 883.122 us; speedup vs baseline: 1.0121x; 1.0121x over previous
//
#include <hip/hip_runtime.h>
#include <stdint.h>

#define HID 2048
#define HKK 8                          // HID / (64 lanes * 4 floats)
#define HSQ ((size_t)HID * HID)        // one gate-block of a weight matrix
#define LSTR ((size_t)4 * HID * HID)   // per-layer stride of W_ih/W_hh
#define GROWS (4 * HID)                // 8192 gate-rows per matrix
#define NOPS 8
#define MSZ ((size_t)GROWS * HID)      // 16777216 elements per weight matrix

// ws layout (float offsets)
#define OFF_H0   0                     // [2][HID] ping-pong
#define OFF_H1   4096                  // [HID]
#define OFF_C0   6144                  // [HID]
#define OFF_C1   8192                  // [HID]
#define OFF_P1   10240                 // [GROWS] layer-1 partial gates
#define OFF_SC   18432                 // lp, ent, sel(int), pad
#define OFF_PIH  18436                 // [9][GROWS] W_ih0@emb + b0
#define WS_FLOATS (OFF_PIH + 9 * GROWS)        // 92164
#define OFF_BW   WS_FLOATS                     // bf16 weights (ushort view)
#define WS_FLOATS_BF (OFF_BW + (3 * MSZ) / 2)

typedef unsigned int uv4_ __attribute__((ext_vector_type(4)));

__device__ __forceinline__ uint32_t rotl32_(uint32_t v, int d) {
  return (v << d) | (v >> (32 - d));
}

// JAX threefry2x32, 20 rounds, key (k0,k1), counter (x0,x1)
__device__ __forceinline__ void tf2x32(uint32_t k0, uint32_t k1,
                                       uint32_t x0, uint32_t x1,
                                       uint32_t& o0, uint32_t& o1) {
  uint32_t k2 = k0 ^ k1 ^ 0x1BD11BDAu;
  x0 += k0; x1 += k1;
#define TFR(r) { x0 += x1; x1 = rotl32_(x1, r); x1 ^= x0; }
  TFR(13) TFR(15) TFR(26) TFR(6)
  x0 += k1; x1 += k2 + 1u;
  TFR(17) TFR(29) TFR(16) TFR(24)
  x0 += k2; x1 += k0 + 2u;
  TFR(13) TFR(15) TFR(26) TFR(6)
  x0 += k0; x1 += k1 + 3u;
  TFR(17) TFR(29) TFR(16) TFR(24)
  x0 += k1; x1 += k2 + 4u;
  TFR(13) TFR(15) TFR(26) TFR(6)
  x0 += k2; x1 += k0 + 5u;
#undef TFR
  o0 = x0; o1 = x1;
}

__device__ __forceinline__ float sigm_(float x) { return 1.0f / (1.0f + expf(-x)); }

__device__ __forceinline__ float wave_red(float s) {
#pragma unroll
  for (int o = 32; o > 0; o >>= 1) s += __shfl_xor(s, o, 64);
  return s;
}

__device__ __forceinline__ float blo_(uint32_t u) {
  return __uint_as_float(u << 16);
}
__device__ __forceinline__ float bhi_(uint32_t u) {
  return __uint_as_float(u & 0xffff0000u);
}
__device__ __forceinline__ uint32_t f2b_(float f) {  // fp32 -> bf16 bits, RNE
  uint32_t u = __float_as_uint(f);
  return (u + 0x7fffu + ((u >> 16) & 1u)) >> 16;
}

// non-temporal float4 load (one-shot fp32 weight streams; keep caches for bw)
__device__ __forceinline__ float4 ldnt_f4(const float* p) {
  uv4_ u = __builtin_nontemporal_load((const uv4_*)p);
  float4 r;
  r.x = __uint_as_float(u.x); r.y = __uint_as_float(u.y);
  r.z = __uint_as_float(u.z); r.w = __uint_as_float(u.w);
  return r;
}

// ---------------- fp32 dot helper (fallback path) ----------------
__device__ __forceinline__ void dot4(const float* __restrict__ wrow,
                                     const float* __restrict__ vec,
                                     int lane, float* __restrict__ g4) {
  float4 acc[4];
#pragma unroll
  for (int g = 0; g < 4; ++g) acc[g] = make_float4(0.f, 0.f, 0.f, 0.f);
#pragma unroll
  for (int kk = 0; kk < HKK; ++kk) {
    const int off = kk * 256 + lane * 4;
    const float4 v = *(const float4*)(vec + off);
#pragma unroll
    for (int g = 0; g < 4; ++g) {
      const float4 w = *(const float4*)(wrow + (size_t)g * HSQ + off);
      acc[g].x = fmaf(w.x, v.x, acc[g].x);
      acc[g].y = fmaf(w.y, v.y, acc[g].y);
      acc[g].z = fmaf(w.z, v.z, acc[g].z);
      acc[g].w = fmaf(w.w, v.w, acc[g].w);
    }
  }
#pragma unroll
  for (int g = 0; g < 4; ++g) {
    float s = (acc[g].x + acc[g].y) + (acc[g].z + acc[g].w);
    g4[g] = wave_red(s);
  }
}

// fp32 matvec (NT reads) + inline bf16 conversion write of the 4 rows.
__device__ __forceinline__ void dot4cvt(const float* __restrict__ wrow,
                                        ushort* __restrict__ drow,
                                        const float* __restrict__ vec,
                                        int lane, float* __restrict__ g4) {
  float4 acc[4];
#pragma unroll
  for (int g = 0; g < 4; ++g) acc[g] = make_float4(0.f, 0.f, 0.f, 0.f);
#pragma unroll
  for (int kk = 0; kk < HKK; ++kk) {
    const int off = kk * 256 + lane * 4;
    const float4 v = *(const float4*)(vec + off);
#pragma unroll
    for (int g = 0; g < 4; ++g) {
      const float4 w = ldnt_f4(wrow + (size_t)g * HSQ + off);
      acc[g].x = fmaf(w.x, v.x, acc[g].x);
      acc[g].y = fmaf(w.y, v.y, acc[g].y);
      acc[g].z = fmaf(w.z, v.z, acc[g].z);
      acc[g].w = fmaf(w.w, v.w, acc[g].w);
      uint2 o;
      o.x = f2b_(w.x) | (f2b_(w.y) << 16);
      o.y = f2b_(w.z) | (f2b_(w.w) << 16);
      *(uint2*)(drow + (size_t)g * HSQ + off) = o;  // 8B-aligned (off%4==0)
    }
  }
#pragma unroll
  for (int g = 0; g < 4; ++g) {
    float s = (acc[g].x + acc[g].y) + (acc[g].z + acc[g].w);
    g4[g] = wave_red(s);
  }
}

// ---------------- bf16 dot helper (R8/R10-proven) ----------------
__device__ __forceinline__ void dot4b(const ushort* __restrict__ wrow,
                                      const float* __restrict__ vec,
                                      int lane, float* __restrict__ g4) {
  uint4 w[4][4];
  float4 v0[4], v1[4];
#pragma unroll
  for (int kk = 0; kk < 4; ++kk) {
    const int off = kk * 512 + lane * 8;
#pragma unroll
    for (int g = 0; g < 4; ++g)
      w[kk][g] = *(const uint4*)(wrow + (size_t)g * HSQ + off);
    v0[kk] = *(const float4*)(vec + off);
    v1[kk] = *(const float4*)(vec + off + 4);
  }
  float4 acc[4];
#pragma unroll
  for (int g = 0; g < 4; ++g) acc[g] = make_float4(0.f, 0.f, 0.f, 0.f);
#pragma unroll
  for (int kk = 0; kk < 4; ++kk) {
#pragma unroll
    for (int g = 0; g < 4; ++g) {
      acc[g].x = fmaf(blo_(w[kk][g].x), v0[kk].x, acc[g].x);
      acc[g].y = fmaf(bhi_(w[kk][g].x), v0[kk].y, acc[g].y);
      acc[g].z = fmaf(blo_(w[kk][g].y), v0[kk].z, acc[g].z);
      acc[g].w = fmaf(bhi_(w[kk][g].y), v0[kk].w, acc[g].w);
      acc[g].x = fmaf(blo_(w[kk][g].z), v1[kk].x, acc[g].x);
      acc[g].y = fmaf(bhi_(w[kk][g].z), v1[kk].y, acc[g].y);
      acc[g].z = fmaf(blo_(w[kk][g].w), v1[kk].z, acc[g].z);
      acc[g].w = fmaf(bhi_(w[kk][g].w), v1[kk].w, acc[g].w);
    }
  }
#pragma unroll
  for (int g = 0; g < 4; ++g) {
    float s = (acc[g].x + acc[g].y) + (acc[g].z + acc[g].w);
    g4[g] = wave_red(s);
  }
}

// ---------------- sampler (shared) ----------------
__device__ __forceinline__ int sample_step(
    const float* __restrict__ w_soft_w, const float* __restrict__ w_soft_b,
    float* __restrict__ out, float* __restrict__ ws, int t, int sidx, int K,
    bool writer) {
  __shared__ float s_raw[NOPS];
  __shared__ int s_sel;
  const int tid = threadIdx.x, lane = tid & 63, wv = tid >> 6;
  const float* h1 = ws + OFF_H1;
  const int r0 = wv * 2, r1 = r0 + 1;
  float4 a0 = make_float4(0.f, 0.f, 0.f, 0.f);
  float4 a1 = make_float4(0.f, 0.f, 0.f, 0.f);
  for (int kk = 0; kk < HKK; ++kk) {
    const int off = kk * 256 + lane * 4;
    const float4 hv = *(const float4*)(h1 + off);
    const float4 wa = *(const float4*)(w_soft_w + (size_t)r0 * HID + off);
    const float4 wb = *(const float4*)(w_soft_w + (size_t)r1 * HID + off);
    a0.x = fmaf(wa.x, hv.x, a0.x); a0.y = fmaf(wa.y, hv.y, a0.y);
    a0.z = fmaf(wa.z, hv.z, a0.z); a0.w = fmaf(wa.w, hv.w, a0.w);
    a1.x = fmaf(wb.x, hv.x, a1.x); a1.y = fmaf(wb.y, hv.y, a1.y);
    a1.z = fmaf(wb.z, hv.z, a1.z); a1.w = fmaf(wb.w, hv.w, a1.w);
  }
  float s0 = wave_red((a0.x + a0.y) + (a0.z + a0.w));
  float s1 = wave_red((a1.x + a1.y) + (a1.z + a1.w));
  if (lane == 0) {
    s_raw[r0] = s0 + w_soft_b[r0];
    s_raw[r1] = s1 + w_soft_b[r1];
  }
  __syncthreads();
  if (tid == 0) {
    float logits[NOPS];
#pragma unroll
    for (int r = 0; r < NOPS; ++r) logits[r] = tanhf(s_raw[r] * 0.2f);
    uint32_t k0, k1;
    tf2x32(0u, 1u, 0u, (uint32_t)t, k0, k1);  // partitionable split
    const float TINY = 1.17549435e-38f;
    int op = 0;
    float best = -1e30f;
#pragma unroll
    for (int r = 0; r < NOPS; ++r) {
      uint32_t o0, o1;
      tf2x32(k0, k1, 0u, (uint32_t)r, o0, o1);  // random_bits: o0^o1
      const uint32_t bits = o0 ^ o1;
      const float f = __uint_as_float((bits >> 9) | 0x3f800000u) - 1.0f;
      const float u = fmaxf(f + TINY, TINY);
      const float g = -logf(-logf(u));
      const float y = g + logits[r];
      if (y > best) { best = y; op = r; }  // first-max (jnp.argmax)
    }
    if (writer) {
      float mx = logits[0];
#pragma unroll
      for (int r = 1; r < NOPS; ++r) mx = fmaxf(mx, logits[r]);
      float se = 0.f;
#pragma unroll
      for (int r = 0; r < NOPS; ++r) se += expf(logits[r] - mx);
      const float lse = mx + logf(se);
      const float lp = ws[OFF_SC] + (logits[op] - lse);
      float es = 0.f;
#pragma unroll
      for (int r = 0; r < NOPS; ++r) {
        const float lr = logits[r] - lse;
        es += expf(lr) * lr;
      }
      const float ent = ws[OFF_SC + 1] - es;
      ws[OFF_SC] = lp;
      ws[OFF_SC + 1] = ent;
      out[sidx] = (float)op;
#pragma unroll
      for (int r = 0; r < NOPS; ++r) out[K + sidx * NOPS + r] = logits[r];
      out[9 * K] = lp;
      out[9 * K + 1] = ent;
    }
    s_sel = op;
  }
  __syncthreads();
  return s_sel;
}

// zero states + scalars
__global__ __launch_bounds__(256) void k_init(float* __restrict__ ws) {
  const int gid = blockIdx.x * 256 + threadIdx.x;
  for (int i = gid; i < OFF_P1; i += gridDim.x * 256) ws[i] = 0.f;
  if (gid < 4) ws[OFF_SC + gid] = 0.f;
}

// pih[k][r] = W_ih0[r,:]@w_emb[k,:] + b_ih0[r] + b_hh0[r]  (NT weight reads)
__global__ __launch_bounds__(256) void k_pre(const float* __restrict__ w_emb,
                                             const float* __restrict__ W_ih,
                                             const float* __restrict__ b_ih,
                                             const float* __restrict__ b_hh,
                                             float* __restrict__ ws) {
  const int tid = threadIdx.x, lane = tid & 63, wv = tid >> 6;
  const int r = blockIdx.x * 4 + wv;  // 0..8191
  const float* wr = W_ih + (size_t)r * HID;
  float4 acc[NOPS + 1];
#pragma unroll
  for (int k = 0; k <= NOPS; ++k) acc[k] = make_float4(0.f, 0.f, 0.f, 0.f);
  for (int kk = 0; kk < HKK; ++kk) {
    const int off = kk * 256 + lane * 4;
    const float4 w = ldnt_f4(wr + off);
#pragma unroll
    for (int k = 0; k <= NOPS; ++k) {
      const float4 e = *(const float4*)(w_emb + (size_t)k * HID + off);
      acc[k].x = fmaf(w.x, e.x, acc[k].x);
      acc[k].y = fmaf(w.y, e.y, acc[k].y);
      acc[k].z = fmaf(w.z, e.z, acc[k].z);
      acc[k].w = fmaf(w.w, e.w, acc[k].w);
    }
  }
  const float bias = b_ih[r] + b_hh[r];
#pragma unroll
  for (int k = 0; k <= NOPS; ++k) {
    float s = (acc[k].x + acc[k].y) + (acc[k].z + acc[k].w);
    s = wave_red(s);
    if (lane == 0) ws[OFF_PIH + (size_t)k * GROWS + r] = s + bias;
  }
}

// step 0 specialization: h0=h1=0 -> gates0 = pih[start], p1 = biases.
__global__ __launch_bounds__(256) void k_s0(const float* __restrict__ b_ih,
                                            const float* __restrict__ b_hh,
                                            float* __restrict__ ws) {
  const int gid = blockIdx.x * 256 + threadIdx.x;
  if (gid < GROWS) {
    ws[OFF_P1 + gid] = 0.f + b_ih[GROWS + gid] + b_hh[GROWS + gid];
  } else if (gid < GROWS + HID) {
    const int j = gid - GROWS;
    const float* pih = ws + OFF_PIH + (size_t)NOPS * GROWS;
    const float gi = pih[j], gf = pih[HID + j];
    const float gg = pih[2 * HID + j], go = pih[3 * HID + j];
    const float ig = sigm_(gi);
    const float fg = sigm_(gf);
    const float g2 = tanhf(gg);
    const float og = sigm_(go);
    const float c = fg * 0.f + ig * g2;
    ws[OFF_C0 + j] = c;
    ws[OFF_H0 + HID + j] = og * tanhf(c);  // par=0 -> h0w = parity 1
  }
}

// step-0 layer-1 finish on fp32 W_ih1 + inline cvt of W_ih1 -> bw. par=0.
__global__ __launch_bounds__(256) void k_b_f32cvt(
    const float* __restrict__ W_ih, ushort* __restrict__ bw,
    float* __restrict__ ws) {
  const int tid = threadIdx.x, lane = tid & 63, wv = tid >> 6;
  const int k = blockIdx.x * 4 + wv;  // 0..2047
  const float* h0n = ws + OFF_H0 + HID;  // parity 1 (written by k_s0)
  float gate[4];
  dot4cvt(W_ih + LSTR + (size_t)k * HID, bw + 2 * MSZ + (size_t)k * HID, h0n,
          lane, gate);
  if (lane == 0) {
#pragma unroll
    for (int g = 0; g < 4; ++g) gate[g] += ws[OFF_P1 + g * HID + k];
    const float ig = sigm_(gate[0]);
    const float fg = sigm_(gate[1]);
    const float gg = tanhf(gate[2]);
    const float og = sigm_(gate[3]);
    const float c = fg * ws[OFF_C1 + k] + ig * gg;
    ws[OFF_C1 + k] = c;
    ws[OFF_H1 + k] = og * tanhf(c);
  }
}

// step-1 phase A on fp32 W_hh + inline cvt of W_hh0/W_hh1 -> bw. par=1.
// flags[0]==0 always -> sel = start token, no sampler needed.
__global__ __launch_bounds__(256) void k_a_f32cvt(
    const float* __restrict__ W_hh, const float* __restrict__ b_ih,
    const float* __restrict__ b_hh, ushort* __restrict__ bw,
    float* __restrict__ ws) {
  const int tid = threadIdx.x, lane = tid & 63, wv = tid >> 6;
  const int gw = blockIdx.x * 4 + wv;  // 0..4095
  const float* h0r = ws + OFF_H0 + HID;  // par=1
  float*       h0w = ws + OFF_H0;        // parity 0

  if (gw < HID) {
    const int j = gw;
    float gate[4];
    dot4cvt(W_hh + (size_t)j * HID, bw + (size_t)j * HID, h0r, lane, gate);
    const float* pih = ws + OFF_PIH + (size_t)NOPS * GROWS;  // start token
#pragma unroll
    for (int g = 0; g < 4; ++g) gate[g] += pih[g * HID + j];
    if (lane == 0) {
      const float ig = sigm_(gate[0]);
      const float fg = sigm_(gate[1]);
      const float gg = tanhf(gate[2]);
      const float og = sigm_(gate[3]);
      const float c = fg * ws[OFF_C0 + j] + ig * gg;
      ws[OFF_C0 + j] = c;
      h0w[j] = og * tanhf(c);
    }
  } else {
    const int k = gw - HID;
    float gate[4];
    dot4cvt(W_hh + LSTR + (size_t)k * HID, bw + MSZ + (size_t)k * HID,
            ws + OFF_H1, lane, gate);
    if (lane == 0) {
#pragma unroll
      for (int g = 0; g < 4; ++g)
        ws[OFF_P1 + g * HID + k] =
            gate[g] + b_ih[GROWS + g * HID + k] + b_hh[GROWS + g * HID + k];
    }
  }
}

// ---- bf16 step kernels (R8/R10-proven structure) ----
__global__ __launch_bounds__(256) void k_a_bf(
    const ushort* __restrict__ bw, const float* __restrict__ b_ih,
    const float* __restrict__ b_hh, const float* __restrict__ w_soft_w,
    const float* __restrict__ w_soft_b, float* __restrict__ out,
    float* __restrict__ ws, int par, int t_prev, int sidx_prev, int K,
    int flag_prev) {
  const int tid = threadIdx.x, lane = tid & 63, wv = tid >> 6;
  const int gw = blockIdx.x * 4 + wv;  // 0..4095
  const float* h0r = ws + OFF_H0 + par * HID;
  float*       h0w = ws + OFF_H0 + (par ^ 1) * HID;

  if (gw < HID) {
    int sel = NOPS;
    if (flag_prev)  // blocks 0..511 only reach here
      sel = sample_step(w_soft_w, w_soft_b, out, ws, t_prev, sidx_prev, K,
                        blockIdx.x == 0);
    const int j = gw;
    float gate[4];
    dot4b(bw + (size_t)j * HID, h0r, lane, gate);  // W_hh0 @ h0
    const float* pih = ws + OFF_PIH + (size_t)sel * GROWS;
#pragma unroll
    for (int g = 0; g < 4; ++g) gate[g] += pih[g * HID + j];
    if (lane == 0) {
      const float ig = sigm_(gate[0]);
      const float fg = sigm_(gate[1]);
      const float gg = tanhf(gate[2]);
      const float og = sigm_(gate[3]);
      const float c = fg * ws[OFF_C0 + j] + ig * gg;
      ws[OFF_C0 + j] = c;
      h0w[j] = og * tanhf(c);
    }
  } else {
    const int k = gw - HID;
    float gate[4];
    dot4b(bw + MSZ + (size_t)k * HID, ws + OFF_H1, lane, gate);  // W_hh1 @ h1
    if (lane == 0) {
#pragma unroll
      for (int g = 0; g < 4; ++g)
        ws[OFF_P1 + g * HID + k] =
            gate[g] + b_ih[GROWS + g * HID + k] + b_hh[GROWS + g * HID + k];
    }
  }
}

__global__ __launch_bounds__(256) void k_b_bf(const ushort* __restrict__ bw,
                                              float* __restrict__ ws, int par) {
  const int tid = threadIdx.x, lane = tid & 63, wv = tid >> 6;
  const int k = blockIdx.x * 4 + wv;  // 0..2047
  const float* h0n = ws + OFF_H0 + (par ^ 1) * HID;
  float gate[4];
  dot4b(bw + 2 * MSZ + (size_t)k * HID, h0n, lane, gate);  // W_ih1 @ h0_new
  if (lane == 0) {
#pragma unroll
    for (int g = 0; g < 4; ++g) gate[g] += ws[OFF_P1 + g * HID + k];
    const float ig = sigm_(gate[0]);
    const float fg = sigm_(gate[1]);
    const float gg = tanhf(gate[2]);
    const float og = sigm_(gate[3]);
    const float c = fg * ws[OFF_C1 + k] + ig * gg;
    ws[OFF_C1 + k] = c;
    ws[OFF_H1 + k] = og * tanhf(c);
  }
}

// ---- fp32 fallback step kernels (R3, proven) ----
template <bool PRE>
__global__ __launch_bounds__(256) void k_a(const float* __restrict__ W_ih,
                                           const float* __restrict__ W_hh,
                                           const float* __restrict__ w_emb,
                                           const float* __restrict__ b_ih,
                                           const float* __restrict__ b_hh,
                                           float* __restrict__ ws, int par,
                                           int dyn) {
  const int tid = threadIdx.x, lane = tid & 63, wv = tid >> 6;
  const int gw = blockIdx.x * 4 + wv;
  const float* h0r = ws + OFF_H0 + par * HID;
  float*       h0w = ws + OFF_H0 + (par ^ 1) * HID;

  if (gw < HID) {
    const int j = gw;
    const int sel = dyn ? *(const int*)(ws + OFF_SC + 2) : NOPS;
    float gate[4];
    dot4(W_hh + (size_t)j * HID, h0r, lane, gate);
    if constexpr (PRE) {
      const float* pih = ws + OFF_PIH + (size_t)sel * GROWS;
#pragma unroll
      for (int g = 0; g < 4; ++g) gate[g] += pih[g * HID + j];
    } else {
      float gi[4];
      dot4(W_ih + (size_t)j * HID, w_emb + (size_t)sel * HID, lane, gi);
#pragma unroll
      for (int g = 0; g < 4; ++g)
        gate[g] += gi[g] + b_ih[g * HID + j] + b_hh[g * HID + j];
    }
    if (lane == 0) {
      const float ig = sigm_(gate[0]);
      const float fg = sigm_(gate[1]);
      const float gg = tanhf(gate[2]);
      const float og = sigm_(gate[3]);
      const float c = fg * ws[OFF_C0 + j] + ig * gg;
      ws[OFF_C0 + j] = c;
      h0w[j] = og * tanhf(c);
    }
  } else {
    const int k = gw - HID;
    float gate[4];
    dot4(W_hh + LSTR + (size_t)k * HID, ws + OFF_H1, lane, gate);
    if (lane == 0) {
#pragma unroll
      for (int g = 0; g < 4; ++g)
        ws[OFF_P1 + g * HID + k] =
            gate[g] + b_ih[GROWS + g * HID + k] + b_hh[GROWS + g * HID + k];
    }
  }
}

__global__ __launch_bounds__(256) void k_b(const float* __restrict__ W_ih,
                                           float* __restrict__ ws, int par) {
  const int tid = threadIdx.x, lane = tid & 63, wv = tid >> 6;
  const int k = blockIdx.x * 4 + wv;
  const float* h0n = ws + OFF_H0 + (par ^ 1) * HID;
  float gate[4];
  dot4(W_ih + LSTR + (size_t)k * HID, h0n, lane, gate);
  if (lane == 0) {
#pragma unroll
    for (int g = 0; g < 4; ++g) gate[g] += ws[OFF_P1 + g * HID + k];
    const float ig = sigm_(gate[0]);
    const float fg = sigm_(gate[1]);
    const float gg = tanhf(gate[2]);
    const float og = sigm_(gate[3]);
    const float c = fg * ws[OFF_C1 + k] + ig * gg;
    ws[OFF_C1 + k] = c;
    ws[OFF_H1 + k] = og * tanhf(c);
  }
}

__global__ __launch_bounds__(256) void k_c(const float* __restrict__ w_soft_w,
                                           const float* __restrict__ w_soft_b,
                                           float* __restrict__ out,
                                           float* __restrict__ ws, int t,
                                           int sidx, int K) {
  const int op = sample_step(w_soft_w, w_soft_b, out, ws, t, sidx, K, true);
  if (threadIdx.x == 0) *(int*)(ws + OFF_SC + 2) = op;
}

extern "C" void kernel_launch(void* const* d_in, const int* in_sizes, int n_in,
                              void* d_out, int out_size, void* d_ws, size_t ws_size,
                              hipStream_t stream) {
  const float* w_emb    = (const float*)d_in[0];
  const float* W_ih     = (const float*)d_in[1];
  const float* W_hh     = (const float*)d_in[2];
  const float* b_ih     = (const float*)d_in[3];
  const float* b_hh     = (const float*)d_in[4];
  const float* w_soft_w = (const float*)d_in[5];
  const float* w_soft_b = (const float*)d_in[6];
  float* out            = (float*)d_out;
  float* ws             = (float*)d_ws;
  ushort* bw            = (ushort*)(ws + OFF_BW);

  // out_size = 9*K + 2 -> K -> n_nodes; schedule is host-static.
  const int K = (out_size - 2) / 9;
  int n = 0;
  while (n * (n + 1) / 2 < K) ++n;
  const int T = 2 + K + n;

  int flags[192];
  {
    int idx = 0;
    flags[idx++] = 0;
    flags[idx++] = 0;
    for (int node = 0; node < n; ++node) {
      for (int i = 0; i <= node; ++i) flags[idx++] = 1;
      flags[idx++] = 0;
    }
  }

  const bool pre = ws_size >= (size_t)WS_FLOATS * sizeof(float);
  const bool bf  = ws_size >= (size_t)WS_FLOATS_BF * sizeof(float);

  k_init<<<64, 256, 0, stream>>>(ws);
  if (pre) k_pre<<<2048, 256, 0, stream>>>(w_emb, W_ih, b_ih, b_hh, ws);

  if (bf && T >= 3) {
    // step 0: no weight matvecs for L0; L1fin on fp32 W_ih1 with inline cvt.
    k_s0<<<(GROWS + HID + 255) / 256, 256, 0, stream>>>(b_ih, b_hh, ws);
    k_b_f32cvt<<<512, 256, 0, stream>>>(W_ih, bw, ws);
    // step 1 (flags[0]==0 -> start token): phase A on fp32 W_hh + inline cvt.
    k_a_f32cvt<<<1024, 256, 0, stream>>>(W_hh, b_ih, b_hh, bw, ws);
    k_b_bf<<<512, 256, 0, stream>>>(bw, ws, 1);
    // steps 2..T-1: all-bf16 (R8-proven loop). par for t=2 is 0.
    int par = 0, cnt = 0, pf = flags[1], pidx = 0;
    for (int t = 2; t < T; ++t) {
      k_a_bf<<<1024, 256, 0, stream>>>(bw, b_ih, b_hh, w_soft_w, w_soft_b,
                                       out, ws, par, t - 1, pidx, K, pf);
      k_b_bf<<<512, 256, 0, stream>>>(bw, ws, par);
      if (flags[t]) { pidx = cnt; ++cnt; }
      pf = flags[t];
      par ^= 1;
    }
    return;
  }

  int par = 0, sidx = 0, prevflag = 0;
  for (int t = 0; t < T; ++t) {
    if (pre)
      k_a<true><<<1024, 256, 0, stream>>>(W_ih, W_hh, w_emb, b_ih, b_hh, ws,
                                          par, prevflag);
    else
      k_a<false><<<1024, 256, 0, stream>>>(W_ih, W_hh, w_emb, b_ih, b_hh, ws,
                                           par, prevflag);
    k_b<<<512, 256, 0, stream>>>(W_ih, ws, par);
    if (flags[t]) {
      k_c<<<1, 256, 0, stream>>>(w_soft_w, w_soft_b, out, ws, t, sidx, K);
      ++sidx;
    }
    prevflag = flags[t];
    par ^= 1;
  }
}